// Round 1
// baseline (48.682 us; speedup 1.0000x reference)
//
#include <hip/hip_runtime.h>
#include <hip/hip_fp16.h>

// Joint bilateral filter, K=5, zero padding.
// t: (2,3,720,1280) f32 guide; v: (2,2,720,1280) f32 flow; out: (2,2,720,1280) f32
// coeff = max(0.875 - 50*sum_c (t_c - ts_c)^2, 0); out = sum(vs*coeff)/sum(coeff)

constexpr int KK  = 5;
constexpr int PAD = 2;
constexpr int N_  = 2;
constexpr int CT  = 3;
constexpr int CV  = 2;
constexpr int H_  = 720;
constexpr int W_  = 1280;
constexpr float COEF0 = 0.875f;  // 1 - |NEG_SS_DIV|
constexpr float SIDIV = 50.0f;   // 1/(2*0.1^2)

__global__ __launch_bounds__(256)
void jbf_kernel(const float* __restrict__ t, const float* __restrict__ v,
                float* __restrict__ out) {
    const int x = blockIdx.x * 256 + threadIdx.x;
    const int y = blockIdx.y;
    const int n = blockIdx.z;
    if (x >= W_) return;

    const int HW = H_ * W_;
    const float* tn = t + (size_t)n * CT * HW;
    const float* vn = v + (size_t)n * CV * HW;
    const int ctr = y * W_ + x;

    const float t0 = tn[ctr];
    const float t1 = tn[HW + ctr];
    const float t2 = tn[2 * HW + ctr];

    float num0 = 0.f, num1 = 0.f, den = 0.f;

    const bool interior = (x >= PAD) && (x < W_ - PAD) && (y >= PAD) && (y < H_ - PAD);

    if (interior) {
        // fast path: no bounds checks, all 25 taps in-bounds
        const float* trow = tn + (y - PAD) * W_ + (x - PAD);
        const float* vrow = vn + (y - PAD) * W_ + (x - PAD);
#pragma unroll
        for (int dy = 0; dy < KK; ++dy) {
            const float* tr = trow + dy * W_;
            const float* vr = vrow + dy * W_;
#pragma unroll
            for (int dx = 0; dx < KK; ++dx) {
                const float s0 = tr[dx];
                const float s1 = tr[HW + dx];
                const float s2 = tr[2 * HW + dx];
                const float d0 = t0 - s0;
                const float d1 = t1 - s1;
                const float d2 = t2 - s2;
                const float diff = d0 * d0 + d1 * d1 + d2 * d2;
                const float c = fmaxf(COEF0 - SIDIV * diff, 0.0f);
                num0 = fmaf(vr[dx], c, num0);
                num1 = fmaf(vr[HW + dx], c, num1);
                den += c;
            }
        }
    } else {
        // boundary path: clamp address (always-valid load), select 0 for OOB taps.
        // OOB taps: ts=0, vs=0 but coeff still accumulates into den (zero padding).
#pragma unroll
        for (int dy = 0; dy < KK; ++dy) {
            const int yy = y + dy - PAD;
            const int yyc = min(max(yy, 0), H_ - 1);
            const bool yin = (unsigned)yy < (unsigned)H_;
#pragma unroll
            for (int dx = 0; dx < KK; ++dx) {
                const int xx = x + dx - PAD;
                const int xxc = min(max(xx, 0), W_ - 1);
                const bool in = yin && ((unsigned)xx < (unsigned)W_);
                const int idx = yyc * W_ + xxc;
                const float s0 = in ? tn[idx] : 0.f;
                const float s1 = in ? tn[HW + idx] : 0.f;
                const float s2 = in ? tn[2 * HW + idx] : 0.f;
                const float w0 = in ? vn[idx] : 0.f;
                const float w1 = in ? vn[HW + idx] : 0.f;
                const float d0 = t0 - s0;
                const float d1 = t1 - s1;
                const float d2 = t2 - s2;
                const float diff = d0 * d0 + d1 * d1 + d2 * d2;
                const float c = fmaxf(COEF0 - SIDIV * diff, 0.0f);
                num0 = fmaf(w0, c, num0);
                num1 = fmaf(w1, c, num1);
                den += c;
            }
        }
    }

    const float r = 1.0f / den;
    float o0 = num0 * r;
    float o1 = num1 * r;
    // mimic the reference's fp16 cast so we match the compared values closely
    o0 = __half2float(__float2half(o0));
    o1 = __half2float(__float2half(o1));

    out[(size_t)(n * CV + 0) * HW + ctr] = o0;
    out[(size_t)(n * CV + 1) * HW + ctr] = o1;
}

extern "C" void kernel_launch(void* const* d_in, const int* in_sizes, int n_in,
                              void* d_out, int out_size, void* d_ws, size_t ws_size,
                              hipStream_t stream) {
    const float* t = (const float*)d_in[0];
    const float* v = (const float*)d_in[1];
    float* out = (float*)d_out;

    dim3 block(256, 1, 1);
    dim3 grid((W_ + 255) / 256, H_, N_);
    jbf_kernel<<<grid, block, 0, stream>>>(t, v, out);
}